// Round 15
// baseline (276.157 us; speedup 1.0000x reference)
//
#include <hip/hip_runtime.h>
#include <hip/hip_bf16.h>

// ---------------------------------------------------------------------------
// Discriminator (HouseGAN-style), fused-LDS MFMA version.
// r15 = r14 with k_mid1 split into per-image HALF blocks (k_mid1h):
// 75.8KB LDS -> 2 blocks/CU, halo-recompute row windows:
//   h=0: stage rows 0..19, c1 rows 0..17, c2 0..16, c3 0..15, ds1 rows 0..7
//   h=1: stage rows 12..31, c1 13..31, c2 14..31, c3 15..31, ds1 rows 8..15
// LDS chunk map: P(c1out,[2][2][19][32]) [0,2432) | S(stage,[2][20][32])
// [2432,3712) | Q(c2out,[2][2][18][32]) [2432,4736) over S | C(c3out,
// [2][17][32]) [0,1088) over P | zero 4736.
// Everything else identical to r14 (passed, 249us).
// ---------------------------------------------------------------------------

#define N_NODES   1024
#define N_GRAPHS  64

typedef __hip_bfloat16 bf16;
typedef __attribute__((ext_vector_type(8)))  short  short8;
typedef __attribute__((ext_vector_type(16))) float  f32x16;

__device__ __forceinline__ float bf2f(unsigned short s) {
    union { unsigned u; float f; } x; x.u = ((unsigned)s) << 16; return x.f;
}
__device__ __forceinline__ unsigned cvtpk(float a, float b) {
    unsigned r;
    asm("v_cvt_pk_bf16_f32 %0, %1, %2" : "=v"(r) : "v"(a), "v"(b));
    return r;
}
__device__ __forceinline__ uint4 pack8(const float* f) {
    uint4 r;
    r.x = cvtpk(f[0], f[1]);
    r.y = cvtpk(f[2], f[3]);
    r.z = cvtpk(f[4], f[5]);
    r.w = cvtpk(f[6], f[7]);
    return r;
}
__device__ __forceinline__ void gload16(const void* g, void* l) {
    __builtin_amdgcn_global_load_lds(
        reinterpret_cast<const __attribute__((address_space(1))) unsigned*>(
            reinterpret_cast<uintptr_t>(g)),
        reinterpret_cast<__attribute__((address_space(3))) unsigned*>(
            reinterpret_cast<uintptr_t>(l)),
        16, 0, 0);
}

template<int N>
__device__ __forceinline__ void zacc(f32x16* a) {
    #pragma unroll
    for (int i = 0; i < N; ++i)
        #pragma unroll
        for (int e = 0; e < 16; ++e) a[i][e] = 0.f;
}

// ---- generic MFMA phase (16 input ch) of a 3x3 conv over an LDS image -----
template<int WIN, int WOUT, int STRIDE, int TPW, int TILES, int NW>
__device__ __forceinline__ void mfma_phase(
    const short* lds, int inbase, int zch,
    const unsigned short* wfb, int kkstride_sh,
    f32x16* acc, int wid, int lane)
{
    constexpr int NPI = WIN * WIN;
    const int pxl = lane & 31, kg = lane >> 5;
    short8 wfr[9];
    #pragma unroll
    for (int kk = 0; kk < 9; ++kk)
        wfr[kk] = *(const short8*)(wfb + (size_t)kk * kkstride_sh + lane * 8);
    #pragma unroll
    for (int kk = 0; kk < 9; ++kk) {
        #pragma unroll
        for (int t = 0; t < TPW; ++t) {
            int tile = wid * TPW + t;
            if (NW * TPW > TILES && tile >= TILES) continue;
            int oy, ox;
            if (WOUT == 32)      { oy = tile;                  ox = pxl;      }
            else if (WOUT == 16) { oy = tile * 2 + (pxl >> 4); ox = pxl & 15; }
            else                 { oy = tile * 4 + (pxl >> 3); ox = pxl & 7;  }
            int iy = STRIDE * oy + kk / 3 - 1, ix = STRIDE * ox + kk % 3 - 1;
            bool ok = ((unsigned)iy < (unsigned)WIN) && ((unsigned)ix < (unsigned)WIN);
            int chunk = ok ? (inbase + kg * NPI + iy * WIN + ix) : zch;
            acc[t] = __builtin_amdgcn_mfma_f32_32x32x16_bf16(
                wfr[kk], *(const short8*)(lds + (size_t)chunk * 8), acc[t], 0, 0, 0);
        }
    }
}

// ---- conv epilogue: bias + optional lrelu, write LDS or global grouped ----
template<int WOUT, int COUT, int RELU, int TPW, int TILES, int NW, bool TOGLOBAL>
__device__ __forceinline__ void conv_epi(
    short* lds, int outbase, unsigned short* gout,
    const float* __restrict__ bias, const f32x16* acc, int wid, int lane)
{
    constexpr int NPO = WOUT * WOUT;
    const int pxl = lane & 31, kg = lane >> 5;
    #pragma unroll
    for (int t = 0; t < TPW; ++t) {
        int tile = wid * TPW + t;
        if (NW * TPW > TILES && tile >= TILES) continue;
        int oy, ox;
        if (WOUT == 32)      { oy = tile;                  ox = pxl;      }
        else if (WOUT == 16) { oy = tile * 2 + (pxl >> 4); ox = pxl & 15; }
        else                 { oy = tile * 4 + (pxl >> 3); ox = pxl & 7;  }
        int opx = oy * WOUT + ox;
        #pragma unroll
        for (int q = 0; q < COUT / 8; ++q) {
            float v[4];
            #pragma unroll
            for (int j = 0; j < 4; ++j) {
                int co = q * 8 + kg * 4 + j;
                float x = acc[t][4 * q + j] + bias[co];
                v[j] = RELU ? ((x >= 0.f) ? x : 0.1f * x) : x;
            }
            uint2 pk;
            pk.x = cvtpk(v[0], v[1]);
            pk.y = cvtpk(v[2], v[3]);
            if constexpr (TOGLOBAL)
                *(uint2*)(gout + ((size_t)q * NPO + opx) * 8 + kg * 4) = pk;
            else
                *(uint2*)(lds + ((size_t)(outbase + q * NPO + opx)) * 8 + kg * 4) = pk;
        }
    }
}

// ---- row-window MFMA for k_mid1h (stride-1, 32px rows, TPW=3) -------------
// Output rows or0..or0+orn-1 (absolute); input buffer holds rows ir0.. with
// per-8ch-group stride gstride chunks; 16 input ch per call.
__device__ __forceinline__ void mfma_rows(
    const short* lds, int inbase, int gstride, int zch,
    const unsigned short* wfb, int kkstride_sh,
    f32x16* acc, int wid, int lane, int or0, int orn, int ir0)
{
    const int pxl = lane & 31, kg = lane >> 5;
    short8 wfr[9];
    #pragma unroll
    for (int kk = 0; kk < 9; ++kk)
        wfr[kk] = *(const short8*)(wfb + (size_t)kk * kkstride_sh + lane * 8);
    #pragma unroll
    for (int kk = 0; kk < 9; ++kk) {
        #pragma unroll
        for (int t = 0; t < 3; ++t) {
            int tile = wid * 3 + t;
            if (tile >= orn) continue;            // wave-uniform
            int oy = or0 + tile;
            int iy = oy + kk / 3 - 1, ix = pxl + kk % 3 - 1;
            bool ok = ((unsigned)iy < 32u) && ((unsigned)ix < 32u);
            int chunk = ok ? (inbase + kg * gstride + (iy - ir0) * 32 + ix) : zch;
            acc[t] = __builtin_amdgcn_mfma_f32_32x32x16_bf16(
                wfr[kk], *(const short8*)(lds + (size_t)chunk * 8), acc[t], 0, 0, 0);
        }
    }
}

// ---- row-window epilogue to LDS (no relu), nq 8-ch output groups ----------
__device__ __forceinline__ void epi_rows(
    short* lds, int outbase, int sstride, int gstride,
    const float* __restrict__ bias, const f32x16* acc,
    int wid, int lane, int or0, int orn, int nq)
{
    const int pxl = lane & 31, kg = lane >> 5;
    #pragma unroll
    for (int t = 0; t < 3; ++t) {
        int tile = wid * 3 + t;
        if (tile >= orn) continue;
        int lr = tile;                             // oy - or0
        for (int q = 0; q < nq; ++q) {
            float v[4];
            #pragma unroll
            for (int j = 0; j < 4; ++j) {
                int co = q * 8 + kg * 4 + j;
                v[j] = acc[t][4 * q + j] + bias[co];
            }
            uint2 pk;
            pk.x = cvtpk(v[0], v[1]);
            pk.y = cvtpk(v[2], v[3]);
            *(uint2*)(lds + ((size_t)(outbase + (q >> 1) * sstride + (q & 1) * gstride
                      + lr * 32 + pxl)) * 8 + kg * 4) = pk;
        }
    }
}

// ---------------- k_setup: weight prep + adjacency + out init (1 launch) ---
#define N_PREP 14
struct PrepArgs {
    const float* w[N_PREP];
    unsigned short* o[N_PREP];
    int cin[N_PREP], cout[N_PREP], cig[N_PREP], mt[N_PREP], base[N_PREP];
    int prep_total;
    const int* edges; int per_g;
    int* adj_cnt; int* adj_lst;
    float* out; const float* pb;
};

__global__ __launch_bounds__(64) void k_setup(PrepArgs a)
{
    int b = blockIdx.x;
    int tid = threadIdx.x;
    if (b < a.prep_total) {
        int L = 0;
        #pragma unroll
        for (int i = 1; i < N_PREP; ++i) if (b >= a.base[i]) L = i;
        int rel = b - a.base[L];
        int MT = a.mt[L], CIG = a.cig[L];
        int m = rel % MT; rel /= MT;
        int cg = rel % CIG;
        int kk = rel / CIG;
        int Cin = a.cin[L], Cout = a.cout[L];
        int co = m * 32 + (tid & 31), kg = tid >> 5;
        float v[8];
        #pragma unroll
        for (int j = 0; j < 8; ++j) {
            int ci = cg * 16 + kg * 8 + j;
            v[j] = (co < Cout && ci < Cin) ? a.w[L][((size_t)co * Cin + ci) * 9 + kk] : 0.f;
        }
        *(uint4*)(a.o[L] + ((size_t)((kk * CIG + cg) * MT + m) * 64 + tid) * 8) = pack8(v);
    } else if (b < a.prep_total + 16) {
        int n = (b - a.prep_total) * 64 + tid;
        int g = n >> 4;
        const int* eg = a.edges + (size_t)g * a.per_g * 3;
        int c = 0;
        for (int k = 0; k < a.per_g; ++k) {
            int aa = eg[k * 3 + 0];
            int s  = eg[k * 3 + 1];
            int bb = eg[k * 3 + 2];
            int other = (aa == n) ? bb : ((bb == n) ? aa : -1);
            if (other >= 0 && (other >> 4) == g && c < 16) {
                a.adj_lst[n * 16 + c] = other | ((s < 0) ? (int)0x80000000 : 0);
                ++c;
            }
        }
        a.adj_cnt[n] = c;
    } else {
        if (tid < N_GRAPHS) a.out[tid] = a.pb[0];
    }
}

// ---------------- k_front: embed + c1 + c2 + c3 fused (8 waves) ------------
__global__ __launch_bounds__(512) void k_front(
    const float* __restrict__ x, const float* __restrict__ t,
    const float* __restrict__ wt, const float* __restrict__ bt,
    const unsigned short* __restrict__ wf1, const float* __restrict__ b1,
    const unsigned short* __restrict__ wf2, const float* __restrict__ b2,
    const unsigned short* __restrict__ wf3, const float* __restrict__ b3,
    bf16* __restrict__ c3o, int node_base)
{
    // chunks: bufA [0,2048), bufB [2048,4096), zero 4096
    __shared__ __align__(16) short lds[4097 * 8];
    __shared__ float s_t[10];
    const int nl = blockIdx.x, n = node_base + nl, tid = threadIdx.x;
    const int wid = tid >> 6, lane = tid & 63;
    if (tid < 10) s_t[tid] = t[n * 10 + tid];
    if (tid < 8)  lds[4096 * 8 + tid] = 0;
    __syncthreads();

    // embed -> bufA (16 ch: x | 8 t-proj | zeros)
    #pragma unroll
    for (int p = 0; p < 2; ++p) {
        int px = tid + p * 512;
        float ch[16];
        ch[0] = x[(size_t)n * 1024 + px];
        #pragma unroll
        for (int c = 1; c <= 8; ++c) {
            int o = (c - 1) * 1024 + px;
            float a = bt[o];
            const float* wr = wt + (size_t)o * 10;
            #pragma unroll
            for (int k = 0; k < 10; ++k) a += wr[k] * s_t[k];
            ch[c] = a;
        }
        #pragma unroll
        for (int c = 9; c < 16; ++c) ch[c] = 0.f;
        *(uint4*)(lds + (size_t)px * 8)          = pack8(ch);
        *(uint4*)(lds + (size_t)(1024 + px) * 8) = pack8(ch + 8);
    }
    __syncthreads();

    f32x16 acc[4];
    // c1: A -> B, relu
    zacc<4>(acc);
    mfma_phase<32, 32, 1, 4, 32, 8>(lds, 0, 4096, wf1, 512, acc, wid, lane);
    conv_epi<32, 16, 1, 4, 32, 8, false>(lds, 2048, nullptr, b1, acc, wid, lane);
    __syncthreads();
    // c2: B -> A, relu
    zacc<4>(acc);
    mfma_phase<32, 32, 1, 4, 32, 8>(lds, 2048, 4096, wf2, 512, acc, wid, lane);
    conv_epi<32, 16, 1, 4, 32, 8, false>(lds, 0, nullptr, b2, acc, wid, lane);
    __syncthreads();
    // c3: A -> global, relu
    zacc<4>(acc);
    mfma_phase<32, 32, 1, 4, 32, 8>(lds, 0, 4096, wf3, 512, acc, wid, lane);
    conv_epi<32, 16, 1, 4, 32, 8, true>(lds, 0,
        (unsigned short*)c3o + (size_t)nl * 16384, b3, acc, wid, lane);
}

// ---------------- k_mid1h: m1 chain + ds1, HALF image per block ------------
// grid (nc, 2); 512 threads; 75.8KB LDS -> 2 blocks/CU.
__global__ __launch_bounds__(512) void k_mid1h(
    const bf16* __restrict__ c3o, const bf16* __restrict__ g1p,
    const unsigned short* __restrict__ wf1, const float* __restrict__ b1,
    const unsigned short* __restrict__ wf2, const float* __restrict__ b2,
    const unsigned short* __restrict__ wf3, const float* __restrict__ b3,
    const unsigned short* __restrict__ wfd, const float* __restrict__ bd,
    bf16* __restrict__ ds1o)
{
    // chunk map: P [0,2432)  S [2432,3712)  Q [2432,4736)  C [0,1088)  z 4736
    __shared__ __align__(16) short lds[4737 * 8];
    const int nl = blockIdx.x, h = blockIdx.y, tid = threadIdx.x;
    const int wid = tid >> 6, lane = tid & 63;
    const int pxl = lane & 31, kg = lane >> 5;
    if (tid < 8) lds[4736 * 8 + tid] = 0;

    const int in_r0 = h ? 12 : 0;                 // stage rows in_r0..in_r0+19
    const int c1_r0 = h ? 13 : 0, orn1 = h ? 19 : 18;
    const int c2_r0 = h ? 14 : 0, orn2 = h ? 18 : 17;
    const int c3_r0 = h ? 15 : 0, orn3 = h ? 17 : 16;

    constexpr int P0 = 0,    PS = 2 * 19 * 32, PG = 19 * 32;   // c1out strides
    constexpr int S0 = 2432, SG = 20 * 32;                      // stage
    constexpr int Q0 = 2432, QS = 2 * 18 * 32, QG = 18 * 32;   // c2out
    constexpr int C0 = 0,    CG = 17 * 32;                      // c3out
    constexpr int ZCH = 4736;

    const uint4* selfp = (const uint4*)c3o + (size_t)nl * 2048;
    const uint4* posp  = (const uint4*)g1p + (size_t)nl * 4096;
    const uint4* negp  = posp + 2048;

    // stage helper: 1280 chunks, layout [g][20][32] linear; src row in_r0+r
    // src chunk = g*1024 + in_r0*32 + (i - g*640)
    #define STAGE(srcbase)                                                    \
        {                                                                     \
            int i0 = tid;          gload16((srcbase) + (i0 < 640 ? i0 : 384 + i0), \
                                           (uint4*)lds + S0 + i0);            \
            int i1 = tid + 512;    gload16((srcbase) + (i1 < 640 ? i1 : 384 + i1), \
                                           (uint4*)lds + S0 + i1);            \
            if (tid < 256) {                                                  \
                int i2 = tid + 1024;                                          \
                gload16((srcbase) + 384 + i2, (uint4*)lds + S0 + i2);         \
            }                                                                 \
        }
    // note: for i in group g: src = g*1024 + in_r0*32 + (i - g*640)
    //       = i + g*384 + in_r0*32.  (g = i>=640)

    const uint4* s_self = selfp + in_r0 * 32;
    const uint4* s_pos  = posp  + in_r0 * 32;
    const uint4* s_neg  = negp  + in_r0 * 32;

    f32x16 acc[3];
    zacc<3>(acc);

    STAGE(s_self);
    __syncthreads();
    mfma_rows(lds, S0, SG, ZCH, wf1,        3 * 512, acc, wid, lane, c1_r0, orn1, in_r0);
    __syncthreads();
    STAGE(s_pos);
    __syncthreads();
    mfma_rows(lds, S0, SG, ZCH, wf1 + 512,  3 * 512, acc, wid, lane, c1_r0, orn1, in_r0);
    __syncthreads();
    STAGE(s_neg);
    __syncthreads();
    mfma_rows(lds, S0, SG, ZCH, wf1 + 1024, 3 * 512, acc, wid, lane, c1_r0, orn1, in_r0);
    epi_rows(lds, P0, PS, PG, b1, acc, wid, lane, c1_r0, orn1, 4);
    __syncthreads();

    // m1c2: P -> Q
    zacc<3>(acc);
    mfma_rows(lds, P0,      PG, ZCH, wf2,       2 * 512, acc, wid, lane, c2_r0, orn2, c1_r0);
    mfma_rows(lds, P0 + PS, PG, ZCH, wf2 + 512, 2 * 512, acc, wid, lane, c2_r0, orn2, c1_r0);
    epi_rows(lds, Q0, QS, QG, b2, acc, wid, lane, c2_r0, orn2, 4);
    __syncthreads();

    // m1c3: Q -> C
    zacc<3>(acc);
    mfma_rows(lds, Q0,      QG, ZCH, wf3,       2 * 512, acc, wid, lane, c3_r0, orn3, c2_r0);
    mfma_rows(lds, Q0 + QS, QG, ZCH, wf3 + 512, 2 * 512, acc, wid, lane, c3_r0, orn3, c2_r0);
    epi_rows(lds, C0, 0, CG, b3, acc, wid, lane, c3_r0, orn3, 2);
    __syncthreads();

    // ds1: C (rows c3_r0.., 32px rows) -> global rows 8h..8h+7, relu
    {
        f32x16 a0;
        #pragma unroll
        for (int e = 0; e < 16; ++e) a0[e] = 0.f;
        short8 wfr[9];
        #pragma unroll
        for (int kk = 0; kk < 9; ++kk)
            wfr[kk] = *(const short8*)(wfd + (size_t)kk * 512 + lane * 8);
        if (wid < 4) {
            int oy = 8 * h + wid * 2 + (pxl >> 4);
            int ox = pxl & 15;
            #pragma unroll
            for (int kk = 0; kk < 9; ++kk) {
                int iy = 2 * oy + kk / 3 - 1, ix = 2 * ox + kk % 3 - 1;
                bool ok = ((unsigned)iy < 32u) && ((unsigned)ix < 32u);
                int chunk = ok ? (C0 + kg * CG + (iy - c3_r0) * 32 + ix) : ZCH;
                a0 = __builtin_amdgcn_mfma_f32_32x32x16_bf16(
                    wfr[kk], *(const short8*)(lds + (size_t)chunk * 8), a0, 0, 0, 0);
            }
            unsigned short* gout = (unsigned short*)ds1o + (size_t)nl * 4096;
            int opx = oy * 16 + ox;
            #pragma unroll
            for (int q = 0; q < 2; ++q) {
                float v[4];
                #pragma unroll
                for (int j = 0; j < 4; ++j) {
                    int co = q * 8 + kg * 4 + j;
                    float xx = a0[4 * q + j] + bd[co];
                    v[j] = (xx >= 0.f) ? xx : 0.1f * xx;
                }
                uint2 pk;
                pk.x = cvtpk(v[0], v[1]);
                pk.y = cvtpk(v[2], v[3]);
                *(uint2*)(gout + ((size_t)q * 256 + opx) * 8 + kg * 4) = pk;
            }
        }
    }
    #undef STAGE
}

// ---------------- k_mid2: m2c1 + m2c2 + m2c3 + ds2 fused (8 waves) ---------
__global__ __launch_bounds__(512) void k_mid2(
    const bf16* __restrict__ ds1o, const bf16* __restrict__ g2p,
    const unsigned short* __restrict__ wf1, const float* __restrict__ b1,
    const unsigned short* __restrict__ wf2, const float* __restrict__ b2,
    const unsigned short* __restrict__ wf3, const float* __restrict__ b3,
    const unsigned short* __restrict__ wfd, const float* __restrict__ bd,
    bf16* __restrict__ ds2o)
{
    // chunks: stageA [0,512), stageB [512,1024), bufX [1024,2048),
    //         bufY [0,1024), m2c3-out [1024,1536), zero 2048
    __shared__ __align__(16) short lds[2049 * 8];
    const int nl = blockIdx.x, tid = threadIdx.x;
    const int wid = tid >> 6, lane = tid & 63;
    if (tid < 8) lds[2048 * 8 + tid] = 0;

    uint4* l4 = (uint4*)lds;
    const uint4* s0 = (const uint4*)ds1o + (size_t)nl * 512;
    const uint4* s1 = (const uint4*)g2p + (size_t)nl * 1024;
    const uint4* s2 = s1 + 512;
    l4[tid] = s0[tid];
    __syncthreads();

    f32x16 acc[1];
    zacc<1>(acc);
    uint4 pf;
    pf = s1[tid];
    mfma_phase<16, 16, 1, 1, 8, 8>(lds, 0, 2048, wf1, 3 * 512, acc, wid, lane);
    l4[512 + tid] = pf;
    __syncthreads();
    pf = s2[tid];
    mfma_phase<16, 16, 1, 1, 8, 8>(lds, 512, 2048, wf1 + 512, 3 * 512, acc, wid, lane);
    l4[tid] = pf;
    __syncthreads();
    mfma_phase<16, 16, 1, 1, 8, 8>(lds, 0, 2048, wf1 + 1024, 3 * 512, acc, wid, lane);
    conv_epi<16, 32, 0, 1, 8, 8, false>(lds, 1024, nullptr, b1, acc, wid, lane);
    __syncthreads();

    zacc<1>(acc);
    mfma_phase<16, 16, 1, 1, 8, 8>(lds, 1024, 2048, wf2,       2 * 512, acc, wid, lane);
    mfma_phase<16, 16, 1, 1, 8, 8>(lds, 1536, 2048, wf2 + 512, 2 * 512, acc, wid, lane);
    conv_epi<16, 32, 0, 1, 8, 8, false>(lds, 0, nullptr, b2, acc, wid, lane);
    __syncthreads();

    zacc<1>(acc);
    mfma_phase<16, 16, 1, 1, 8, 8>(lds, 0,   2048, wf3,       2 * 512, acc, wid, lane);
    mfma_phase<16, 16, 1, 1, 8, 8>(lds, 512, 2048, wf3 + 512, 2 * 512, acc, wid, lane);
    conv_epi<16, 16, 0, 1, 8, 8, false>(lds, 1024, nullptr, b3, acc, wid, lane);
    __syncthreads();

    zacc<1>(acc);
    mfma_phase<16, 8, 2, 1, 2, 8>(lds, 1024, 2048, wfd, 512, acc, wid, lane);
    conv_epi<8, 16, 1, 1, 2, 8, true>(lds, 0,
        (unsigned short*)ds2o + (size_t)nl * 1024, bd, acc, wid, lane);
}

// ---------------- read-once LDS gather: pos/neg sums only ------------------
template<int NPIX>
__global__ __launch_bounds__(256) void k_gather2(
    const bf16* __restrict__ in, const int* __restrict__ cnt,
    const int* __restrict__ lst, bf16* __restrict__ out, int node_base)
{
    constexpr int CPN = 2 * NPIX;
    __shared__ __align__(16) uint4 s_in[16 * 128];
    __shared__ int s_pos[16], s_neg[16];

    const int gl = blockIdx.x, sp = blockIdx.y, tid = threadIdx.x;
    const int gn0 = node_base + gl * 16, nl0 = gl * 16;

    if (tid < 16) {
        int c = cnt[gn0 + tid]; if (c > 16) c = 16;
        int pm = 0, nm = 0;
        for (int k = 0; k < c; ++k) {
            int e = lst[(size_t)(gn0 + tid) * 16 + k];
            int sl = (e & 0x7FFFFFFF) - gn0;
            if ((unsigned)sl < 16u) { if (e < 0) nm |= 1 << sl; else pm |= 1 << sl; }
        }
        s_pos[tid] = pm; s_neg[tid] = nm;
    }
    const uint4* in4 = (const uint4*)in;
    #pragma unroll
    for (int k = 0; k < 8; ++k) {
        int i = tid + k * 256;
        int srcn = i >> 7, chk = i & 127;
        gload16(&in4[(size_t)(nl0 + srcn) * CPN + sp * 128 + chk], &s_in[i]);
    }
    __syncthreads();

    const int dh = tid >> 7, ch = tid & 127;
    int pm[8], nm[8];
    #pragma unroll
    for (int dl = 0; dl < 8; ++dl) {
        pm[dl] = __builtin_amdgcn_readfirstlane(s_pos[dh * 8 + dl]);
        nm[dl] = __builtin_amdgcn_readfirstlane(s_neg[dh * 8 + dl]);
    }

    float aP[8][8], aN[8][8];
    #pragma unroll
    for (int dl = 0; dl < 8; ++dl)
        #pragma unroll
        for (int j = 0; j < 8; ++j) { aP[dl][j] = 0.f; aN[dl][j] = 0.f; }

    for (int s = 0; s < 16; ++s) {
        union { uint4 v; unsigned short u[8]; } q;
        q.v = s_in[s * 128 + ch];
        float f[8];
        #pragma unroll
        for (int j = 0; j < 8; ++j) f[j] = bf2f(q.u[j]);
        #pragma unroll
        for (int dl = 0; dl < 8; ++dl) {
            if ((pm[dl] >> s) & 1) {
                #pragma unroll
                for (int j = 0; j < 8; ++j) aP[dl][j] += f[j];
            }
            if ((nm[dl] >> s) & 1) {
                #pragma unroll
                for (int j = 0; j < 8; ++j) aN[dl][j] += f[j];
            }
        }
    }

    uint4* out4 = (uint4*)out;
    #pragma unroll
    for (int dl = 0; dl < 8; ++dl) {
        int d = nl0 + dh * 8 + dl;
        out4[((size_t)d * 2 + 0) * CPN + sp * 128 + ch] = pack8(aP[dl]);
        out4[((size_t)d * 2 + 1) * CPN + sp * 128 + ch] = pack8(aN[dl]);
    }
}

// ---------------- k_tail3: d1 + d2 + d3 + pool fused (8 img/block) ---------
__global__ __launch_bounds__(512) void k_tail3(
    const bf16* __restrict__ ds2o,
    const unsigned short* __restrict__ w1, const float* __restrict__ b1,
    const unsigned short* __restrict__ w2, const float* __restrict__ b2,
    const unsigned short* __restrict__ w3, const float* __restrict__ b3,
    const int* __restrict__ nd, const float* __restrict__ pw,
    float* __restrict__ out, int node_base)
{
    __shared__ __align__(16) short lds[5121 * 8];
    __shared__ float s_part[4][8];
    const int tid = threadIdx.x, wid = tid >> 6, lane = tid & 63;
    const int col = lane & 31, kg = lane >> 5;
    const int img0 = blockIdx.x * 8;
    if (tid < 8) lds[5120 * 8 + tid] = 0;

    const uint4* src = (const uint4*)ds2o + (size_t)img0 * 128;
    gload16(src + tid,       (uint4*)lds + tid);
    gload16(src + 512 + tid, (uint4*)lds + 512 + tid);
    __syncthreads();

    // d1
    {
        f32x16 acc[4];
        zacc<4>(acc);
        #pragma unroll
        for (int t = 0; t < 4; ++t) {
            int tl = wid + 8 * t;
            int m = tl >> 2, n = tl & 3;
            int idx = n * 32 + col;
            int img = idx >> 4, px = idx & 15;
            int oy = px >> 2, ox = px & 3;
            #pragma unroll
            for (int kk = 0; kk < 9; ++kk) {
                int iy = 2 * oy + kk / 3 - 1, ix = 2 * ox + kk % 3 - 1;
                bool ok = ((unsigned)iy < 8u) && ((unsigned)ix < 8u);
                int chunk = ok ? (img * 128 + kg * 64 + iy * 8 + ix) : 5120;
                short8 wfr = *(const short8*)(w1 + ((size_t)(kk * 8 + m) * 64 + lane) * 8);
                acc[t] = __builtin_amdgcn_mfma_f32_32x32x16_bf16(
                    wfr, *(const short8*)(lds + (size_t)chunk * 8), acc[t], 0, 0, 0);
            }
        }
        #pragma unroll
        for (int t = 0; t < 4; ++t) {
            int tl = wid + 8 * t;
            int m = tl >> 2, n = tl & 3;
            int idx = n * 32 + col;
            int img = idx >> 4, px = idx & 15;
            #pragma unroll
            for (int q = 0; q < 4; ++q) {
                float v[4];
                #pragma unroll
                for (int j = 0; j < 4; ++j) {
                    int co = m * 32 + q * 8 + kg * 4 + j;
                    float x = acc[t][4 * q + j] + b1[co];
                    v[j] = (x >= 0.f) ? x : 0.1f * x;
                }
                uint2 pk;
                pk.x = cvtpk(v[0], v[1]);
                pk.y = cvtpk(v[2], v[3]);
                *(uint2*)(lds + ((size_t)(1024 + img * 512 + (m * 4 + q) * 16 + px)) * 8
                          + kg * 4) = pk;
            }
        }
    }
    __syncthreads();

    // d2
    {
        f32x16 acc;
        #pragma unroll
        for (int e = 0; e < 16; ++e) acc[e] = 0.f;
        int img = col >> 2, px = col & 3;
        int oy = px >> 1, ox = px & 1;
        int poff[9];
        #pragma unroll
        for (int kk = 0; kk < 9; ++kk) {
            int iy = 2 * oy + kk / 3 - 1, ix = 2 * ox + kk % 3 - 1;
            bool ok = ((unsigned)iy < 4u) && ((unsigned)ix < 4u);
            poff[kk] = ok ? (iy * 4 + ix) : -1;
        }
        if (wid < 4) {
            for (int cig = 0; cig < 16; ++cig) {
                #pragma unroll
                for (int kk = 0; kk < 9; ++kk) {
                    short8 wfr = *(const short8*)(w2 +
                        ((size_t)((kk * 16 + cig) * 4 + wid) * 64 + lane) * 8);
                    int chunk = (poff[kk] >= 0)
                              ? 1024 + img * 512 + (cig * 2 + kg) * 16 + poff[kk]
                              : 5120;
                    acc = __builtin_amdgcn_mfma_f32_32x32x16_bf16(
                        wfr, *(const short8*)(lds + (size_t)chunk * 8), acc, 0, 0, 0);
                }
            }
        }
        __syncthreads();
        if (wid < 4) {
            #pragma unroll
            for (int q = 0; q < 4; ++q) {
                float v[4];
                #pragma unroll
                for (int j = 0; j < 4; ++j) {
                    int co = wid * 32 + q * 8 + kg * 4 + j;
                    float x = acc[4 * q + j] + b2[co];
                    v[j] = (x >= 0.f) ? x : 0.1f * x;
                }
                uint2 pk;
                pk.x = cvtpk(v[0], v[1]);
                pk.y = cvtpk(v[2], v[3]);
                *(uint2*)(lds + ((size_t)(img * 64 + (wid * 4 + q) * 4 + px)) * 8
                          + kg * 4) = pk;
            }
        }
    }
    __syncthreads();

    // d3 + pool
    {
        if (wid < 4) {
            int img = col;
            bool live = col < 8;
            f32x16 acc;
            #pragma unroll
            for (int e = 0; e < 16; ++e) acc[e] = 0.f;
            for (int cig = 0; cig < 8; ++cig) {
                #pragma unroll
                for (int kk = 0; kk < 9; ++kk) {
                    int iy = kk / 3 - 1, ix = kk % 3 - 1;
                    bool ok = live && ((unsigned)iy < 2u) && ((unsigned)ix < 2u);
                    int chunk = ok ? (img * 64 + (cig * 2 + kg) * 4 + iy * 2 + ix) : 5120;
                    short8 wfr = *(const short8*)(w3 +
                        ((size_t)((kk * 8 + cig) * 4 + wid) * 64 + lane) * 8);
                    acc = __builtin_amdgcn_mfma_f32_32x32x16_bf16(
                        wfr, *(const short8*)(lds + (size_t)chunk * 8), acc, 0, 0, 0);
                }
            }
            float part = 0.f;
            #pragma unroll
            for (int r = 0; r < 16; ++r) {
                int co = wid * 32 + (r & 3) + 8 * (r >> 2) + 4 * kg;
                float v = acc[r] + b3[co];
                v = (v >= 0.f) ? v : 0.1f * v;
                part += v * pw[co];
            }
            part += __shfl_xor(part, 32, 64);
            if (kg == 0 && live) s_part[wid][col] = part;
        }
        __syncthreads();
        if (tid < 8) {
            float s = s_part[0][tid] + s_part[1][tid] + s_part[2][tid] + s_part[3][tid];
            int g = nd[node_base + img0 + tid];
            if (g < 0) g = 0; if (g >= N_GRAPHS) g = N_GRAPHS - 1;
            atomicAdd(&out[g], s);
        }
    }
}

// ---------------------------------------------------------------------------
extern "C" void kernel_launch(void* const* d_in, const int* in_sizes, int n_in,
                              void* d_out, int out_size, void* d_ws, size_t ws_size,
                              hipStream_t stream)
{
    const float* x     = (const float*)d_in[0];
    const float* t     = (const float*)d_in[1];
    const int*   edges = (const int*)d_in[2];
    const int*   nd    = (const int*)d_in[3];
    const float* w_t   = (const float*)d_in[4];
    const float* b_t   = (const float*)d_in[5];
    const float* c1w   = (const float*)d_in[6];
    const float* c1b   = (const float*)d_in[7];
    const float* c2w   = (const float*)d_in[8];
    const float* c2b   = (const float*)d_in[9];
    const float* c3w   = (const float*)d_in[10];
    const float* c3b   = (const float*)d_in[11];
    const float* m1c1w = (const float*)d_in[12];
    const float* m1c1b = (const float*)d_in[13];
    const float* m1c2w = (const float*)d_in[14];
    const float* m1c2b = (const float*)d_in[15];
    const float* m1c3w = (const float*)d_in[16];
    const float* m1c3b = (const float*)d_in[17];
    const float* ds1w  = (const float*)d_in[18];
    const float* ds1b  = (const float*)d_in[19];
    const float* m2c1w = (const float*)d_in[20];
    const float* m2c1b = (const float*)d_in[21];
    const float* m2c2w = (const float*)d_in[22];
    const float* m2c2b = (const float*)d_in[23];
    const float* m2c3w = (const float*)d_in[24];
    const float* m2c3b = (const float*)d_in[25];
    const float* ds2w  = (const float*)d_in[26];
    const float* ds2b  = (const float*)d_in[27];
    const float* d1w   = (const float*)d_in[28];
    const float* d1b   = (const float*)d_in[29];
    const float* d2w   = (const float*)d_in[30];
    const float* d2b   = (const float*)d_in[31];
    const float* d3w   = (const float*)d_in[32];
    const float* d3b   = (const float*)d_in[33];
    const float* pw    = (const float*)d_in[34];
    const float* pb    = (const float*)d_in[35];
    float* out = (float*)d_out;

    uint8_t* ws = (uint8_t*)d_ws;
    int* adj_cnt = (int*)ws;                         // [0, 4K)
    int* adj_lst = (int*)(ws + 4096);                // [4K, 68K)
    #define WF(i)  ((unsigned short*)(ws + (128u << 10) + (size_t)(i) * 32768))
    unsigned short* wt_ds1 = (unsigned short*)(ws + (416u  << 10));
    unsigned short* wt_ds2 = (unsigned short*)(ws + (428u  << 10));
    unsigned short* wt_d1  = (unsigned short*)(ws + (440u  << 10));
    unsigned short* wt_d2  = (unsigned short*)(ws + (512u  << 10));
    unsigned short* wt_d3  = (unsigned short*)(ws + (1088u << 10));

    // ---- adaptive chunking: liveness-packed pool, 104 KiB per node --------
    const size_t RESV = 2ull << 20;
    size_t avail = (ws_size > RESV) ? ws_size - RESV : 0;
    int ncap = (int)(avail / (104 * 1024));
    ncap = (ncap / 16) * 16;
    if (ncap < 16) ncap = 16;
    if (ncap > N_NODES) ncap = N_NODES;
    uint8_t* R = ws + RESV;
    #define NB(off_kb) (R + (size_t)(off_kb) * 1024 * ncap)

    bf16*  c3o  = (bf16*)NB(0);     // [0,32)
    bf16*  g1p  = (bf16*)NB(32);    // [32,96)
    bf16*  ds1o = (bf16*)NB(96);    // [96,104)
    bf16*  g2p  = (bf16*)NB(0);     // [0,16)   alias (c3o dead)
    bf16*  ds2o = (bf16*)NB(16);    // [16,18)  alias

    int nE    = in_sizes[2] / 3;
    int per_g = nE / N_GRAPHS;

    // ---- single setup launch ----------------------------------------------
    {
        PrepArgs pa;
        const float* wsrc[N_PREP] = { c1w, c2w, c3w, m1c1w, m1c2w, m1c3w,
                                      m2c1w, m2c2w, m2c3w, ds1w, ds2w,
                                      d1w, d2w, d3w };
        unsigned short* wdst[N_PREP] = { WF(0), WF(1), WF(2), WF(3), WF(4), WF(5),
                                         WF(6), WF(7), WF(8), wt_ds1, wt_ds2,
                                         wt_d1, wt_d2, wt_d3 };
        int cin_[N_PREP]  = { 9, 16, 16, 48, 32, 32, 48, 32, 32, 16, 16, 16, 256, 128 };
        int cout_[N_PREP] = { 16, 16, 16, 32, 32, 16, 32, 32, 16, 16, 16, 256, 128, 128 };
        int cig_[N_PREP]  = { 1, 1, 1, 3, 2, 2, 3, 2, 2, 1, 1, 1, 16, 8 };
        int mt_[N_PREP]   = { 1, 1, 1, 1, 1, 1, 1, 1, 1, 1, 1, 8, 4, 4 };
        int total = 0;
        for (int i = 0; i < N_PREP; ++i) {
            pa.w[i] = wsrc[i]; pa.o[i] = wdst[i];
            pa.cin[i] = cin_[i]; pa.cout[i] = cout_[i];
            pa.cig[i] = cig_[i]; pa.mt[i] = mt_[i];
            pa.base[i] = total;
            total += 9 * cig_[i] * mt_[i];
        }
        pa.prep_total = total;
        pa.edges = edges; pa.per_g = per_g;
        pa.adj_cnt = adj_cnt; pa.adj_lst = adj_lst;
        pa.out = out; pa.pb = pb;
        k_setup<<<total + 16 + 1, 64, 0, stream>>>(pa);
    }

    for (int nb = 0; nb < N_NODES; nb += ncap) {
        int nc = (N_NODES - nb < ncap) ? (N_NODES - nb) : ncap;
        int ng = nc / 16;

        k_front<<<nc, 512, 0, stream>>>(x, t, w_t, b_t,
            WF(0), c1b, WF(1), c2b, WF(2), c3b, c3o, nb);

        k_gather2<1024><<<dim3(ng, 16), 256, 0, stream>>>(c3o, adj_cnt, adj_lst, g1p, nb);

        k_mid1h<<<dim3(nc, 2), 512, 0, stream>>>(c3o, g1p,
            WF(3), m1c1b, WF(4), m1c2b, WF(5), m1c3b, wt_ds1, ds1b, ds1o);

        k_gather2<256><<<dim3(ng, 4), 256, 0, stream>>>(ds1o, adj_cnt, adj_lst, g2p, nb);

        k_mid2<<<nc, 512, 0, stream>>>(ds1o, g2p,
            WF(6), m2c1b, WF(7), m2c2b, WF(8), m2c3b, wt_ds2, ds2b, ds2o);

        k_tail3<<<nc / 8, 512, 0, stream>>>(ds2o,
            wt_d1, d1b, wt_d2, d2b, wt_d3, d3b, nd, pw, out, nb);
    }
    #undef NB
    #undef WF
}

// Round 16
// 246.253 us; speedup vs baseline: 1.1214x; 1.1214x over previous
//
#include <hip/hip_runtime.h>
#include <hip/hip_bf16.h>

// ---------------------------------------------------------------------------
// Discriminator (HouseGAN-style), fused-LDS MFMA version.
// r16 = EXACT r12 (measured best: 246.5us, absmax 0.0635). Reverts the r15
// half-split (halo tax +31% MFMA, 104us) and r13/r14 experiments (null).
// Activations: grouped-HWC bf16  [n][ci/8][px][8ci]  (16B chunks per px).
// MFMA layouts (verified r5): A m=lane&31,k=(lane>>5)*8+j; B col=lane&31;
// C col=lane&31,row=(reg&3)+8*(reg>>2)+4*(lane>>5).
// ---------------------------------------------------------------------------

#define N_NODES   1024
#define N_GRAPHS  64

typedef __hip_bfloat16 bf16;
typedef __attribute__((ext_vector_type(8)))  short  short8;
typedef __attribute__((ext_vector_type(16))) float  f32x16;

__device__ __forceinline__ float bf2f(unsigned short s) {
    union { unsigned u; float f; } x; x.u = ((unsigned)s) << 16; return x.f;
}
__device__ __forceinline__ unsigned cvtpk(float a, float b) {
    unsigned r;
    asm("v_cvt_pk_bf16_f32 %0, %1, %2" : "=v"(r) : "v"(a), "v"(b));
    return r;
}
__device__ __forceinline__ uint4 pack8(const float* f) {
    uint4 r;
    r.x = cvtpk(f[0], f[1]);
    r.y = cvtpk(f[2], f[3]);
    r.z = cvtpk(f[4], f[5]);
    r.w = cvtpk(f[6], f[7]);
    return r;
}
__device__ __forceinline__ void gload16(const void* g, void* l) {
    __builtin_amdgcn_global_load_lds(
        reinterpret_cast<const __attribute__((address_space(1))) unsigned*>(
            reinterpret_cast<uintptr_t>(g)),
        reinterpret_cast<__attribute__((address_space(3))) unsigned*>(
            reinterpret_cast<uintptr_t>(l)),
        16, 0, 0);
}

template<int N>
__device__ __forceinline__ void zacc(f32x16* a) {
    #pragma unroll
    for (int i = 0; i < N; ++i)
        #pragma unroll
        for (int e = 0; e < 16; ++e) a[i][e] = 0.f;
}

// ---- generic MFMA phase (16 input ch) of a 3x3 conv over an LDS image -----
template<int WIN, int WOUT, int STRIDE, int TPW, int TILES, int NW>
__device__ __forceinline__ void mfma_phase(
    const short* lds, int inbase, int zch,
    const unsigned short* wfb, int kkstride_sh,
    f32x16* acc, int wid, int lane)
{
    constexpr int NPI = WIN * WIN;
    const int pxl = lane & 31, kg = lane >> 5;
    short8 wfr[9];
    #pragma unroll
    for (int kk = 0; kk < 9; ++kk)
        wfr[kk] = *(const short8*)(wfb + (size_t)kk * kkstride_sh + lane * 8);
    #pragma unroll
    for (int t = 0; t < TPW; ++t) {
        int tile = wid * TPW + t;
        if (NW * TPW > TILES && tile >= TILES) continue;
        int oy, ox;
        if (WOUT == 32)      { oy = tile;                  ox = pxl;      }
        else if (WOUT == 16) { oy = tile * 2 + (pxl >> 4); ox = pxl & 15; }
        else                 { oy = tile * 4 + (pxl >> 3); ox = pxl & 7;  }
        #pragma unroll
        for (int kk = 0; kk < 9; ++kk) {
            int iy = STRIDE * oy + kk / 3 - 1, ix = STRIDE * ox + kk % 3 - 1;
            bool ok = ((unsigned)iy < (unsigned)WIN) && ((unsigned)ix < (unsigned)WIN);
            int chunk = ok ? (inbase + kg * NPI + iy * WIN + ix) : zch;
            acc[t] = __builtin_amdgcn_mfma_f32_32x32x16_bf16(
                wfr[kk], *(const short8*)(lds + (size_t)chunk * 8), acc[t], 0, 0, 0);
        }
    }
}

// ---- conv epilogue: bias + optional lrelu, write LDS or global grouped ----
template<int WOUT, int COUT, int RELU, int TPW, int TILES, int NW, bool TOGLOBAL>
__device__ __forceinline__ void conv_epi(
    short* lds, int outbase, unsigned short* gout,
    const float* __restrict__ bias, const f32x16* acc, int wid, int lane)
{
    constexpr int NPO = WOUT * WOUT;
    const int pxl = lane & 31, kg = lane >> 5;
    #pragma unroll
    for (int t = 0; t < TPW; ++t) {
        int tile = wid * TPW + t;
        if (NW * TPW > TILES && tile >= TILES) continue;
        int oy, ox;
        if (WOUT == 32)      { oy = tile;                  ox = pxl;      }
        else if (WOUT == 16) { oy = tile * 2 + (pxl >> 4); ox = pxl & 15; }
        else                 { oy = tile * 4 + (pxl >> 3); ox = pxl & 7;  }
        int opx = oy * WOUT + ox;
        #pragma unroll
        for (int q = 0; q < COUT / 8; ++q) {
            float v[4];
            #pragma unroll
            for (int j = 0; j < 4; ++j) {
                int co = q * 8 + kg * 4 + j;
                float x = acc[t][4 * q + j] + bias[co];
                v[j] = RELU ? ((x >= 0.f) ? x : 0.1f * x) : x;
            }
            uint2 pk;
            pk.x = cvtpk(v[0], v[1]);
            pk.y = cvtpk(v[2], v[3]);
            if constexpr (TOGLOBAL)
                *(uint2*)(gout + ((size_t)q * NPO + opx) * 8 + kg * 4) = pk;
            else
                *(uint2*)(lds + ((size_t)(outbase + q * NPO + opx)) * 8 + kg * 4) = pk;
        }
    }
}

// ---------------- k_setup: weight prep + adjacency + out init (1 launch) ---
#define N_PREP 14
struct PrepArgs {
    const float* w[N_PREP];
    unsigned short* o[N_PREP];
    int cin[N_PREP], cout[N_PREP], cig[N_PREP], mt[N_PREP], base[N_PREP];
    int prep_total;
    const int* edges; int per_g;
    int* adj_cnt; int* adj_lst;
    float* out; const float* pb;
};

__global__ __launch_bounds__(64) void k_setup(PrepArgs a)
{
    int b = blockIdx.x;
    int tid = threadIdx.x;
    if (b < a.prep_total) {
        int L = 0;
        #pragma unroll
        for (int i = 1; i < N_PREP; ++i) if (b >= a.base[i]) L = i;
        int rel = b - a.base[L];
        int MT = a.mt[L], CIG = a.cig[L];
        int m = rel % MT; rel /= MT;
        int cg = rel % CIG;
        int kk = rel / CIG;
        int Cin = a.cin[L], Cout = a.cout[L];
        int co = m * 32 + (tid & 31), kg = tid >> 5;
        float v[8];
        #pragma unroll
        for (int j = 0; j < 8; ++j) {
            int ci = cg * 16 + kg * 8 + j;
            v[j] = (co < Cout && ci < Cin) ? a.w[L][((size_t)co * Cin + ci) * 9 + kk] : 0.f;
        }
        *(uint4*)(a.o[L] + ((size_t)((kk * CIG + cg) * MT + m) * 64 + tid) * 8) = pack8(v);
    } else if (b < a.prep_total + 16) {
        int n = (b - a.prep_total) * 64 + tid;
        int g = n >> 4;
        const int* eg = a.edges + (size_t)g * a.per_g * 3;
        int c = 0;
        for (int k = 0; k < a.per_g; ++k) {
            int aa = eg[k * 3 + 0];
            int s  = eg[k * 3 + 1];
            int bb = eg[k * 3 + 2];
            int other = (aa == n) ? bb : ((bb == n) ? aa : -1);
            if (other >= 0 && (other >> 4) == g && c < 16) {
                a.adj_lst[n * 16 + c] = other | ((s < 0) ? (int)0x80000000 : 0);
                ++c;
            }
        }
        a.adj_cnt[n] = c;
    } else {
        if (tid < N_GRAPHS) a.out[tid] = a.pb[0];
    }
}

// ---------------- k_front: embed + c1 + c2 + c3 fused (8 waves) ------------
__global__ __launch_bounds__(512) void k_front(
    const float* __restrict__ x, const float* __restrict__ t,
    const float* __restrict__ wt, const float* __restrict__ bt,
    const unsigned short* __restrict__ wf1, const float* __restrict__ b1,
    const unsigned short* __restrict__ wf2, const float* __restrict__ b2,
    const unsigned short* __restrict__ wf3, const float* __restrict__ b3,
    bf16* __restrict__ c3o, int node_base)
{
    // chunks: bufA [0,2048), bufB [2048,4096), zero 4096
    __shared__ __align__(16) short lds[4097 * 8];
    __shared__ float s_t[10];
    const int nl = blockIdx.x, n = node_base + nl, tid = threadIdx.x;
    const int wid = tid >> 6, lane = tid & 63;
    if (tid < 10) s_t[tid] = t[n * 10 + tid];
    if (tid < 8)  lds[4096 * 8 + tid] = 0;
    __syncthreads();

    // embed -> bufA (16 ch: x | 8 t-proj | zeros)
    #pragma unroll
    for (int p = 0; p < 2; ++p) {
        int px = tid + p * 512;
        float ch[16];
        ch[0] = x[(size_t)n * 1024 + px];
        #pragma unroll
        for (int c = 1; c <= 8; ++c) {
            int o = (c - 1) * 1024 + px;
            float a = bt[o];
            const float* wr = wt + (size_t)o * 10;
            #pragma unroll
            for (int k = 0; k < 10; ++k) a += wr[k] * s_t[k];
            ch[c] = a;
        }
        #pragma unroll
        for (int c = 9; c < 16; ++c) ch[c] = 0.f;
        *(uint4*)(lds + (size_t)px * 8)          = pack8(ch);
        *(uint4*)(lds + (size_t)(1024 + px) * 8) = pack8(ch + 8);
    }
    __syncthreads();

    f32x16 acc[4];
    // c1: A -> B, relu
    zacc<4>(acc);
    mfma_phase<32, 32, 1, 4, 32, 8>(lds, 0, 4096, wf1, 512, acc, wid, lane);
    conv_epi<32, 16, 1, 4, 32, 8, false>(lds, 2048, nullptr, b1, acc, wid, lane);
    __syncthreads();
    // c2: B -> A, relu
    zacc<4>(acc);
    mfma_phase<32, 32, 1, 4, 32, 8>(lds, 2048, 4096, wf2, 512, acc, wid, lane);
    conv_epi<32, 16, 1, 4, 32, 8, false>(lds, 0, nullptr, b2, acc, wid, lane);
    __syncthreads();
    // c3: A -> global, relu
    zacc<4>(acc);
    mfma_phase<32, 32, 1, 4, 32, 8>(lds, 0, 4096, wf3, 512, acc, wid, lane);
    conv_epi<32, 16, 1, 4, 32, 8, true>(lds, 0,
        (unsigned short*)c3o + (size_t)nl * 16384, b3, acc, wid, lane);
}

// ---------------- k_mid1: m1c1 + m1c2 + m1c3 + ds1 fused (8 waves) ---------
__global__ __launch_bounds__(512) void k_mid1(
    const bf16* __restrict__ c3o, const bf16* __restrict__ g1p,
    const unsigned short* __restrict__ wf1, const float* __restrict__ b1,
    const unsigned short* __restrict__ wf2, const float* __restrict__ b2,
    const unsigned short* __restrict__ wf3, const float* __restrict__ b3,
    const unsigned short* __restrict__ wfd, const float* __restrict__ bd,
    bf16* __restrict__ ds1o)
{
    // chunks: stageA [0,2048), stageB [2048,4096), bufX [4096,8192),
    //         bufY [0,4096) (after m1c1), m1c3-out [4096,6144), zero 8192
    __shared__ __align__(16) short lds[8193 * 8];
    const int nl = blockIdx.x, tid = threadIdx.x;
    const int wid = tid >> 6, lane = tid & 63;
    if (tid < 8) lds[8192 * 8 + tid] = 0;

    uint4* l4 = (uint4*)lds;
    const uint4* s0 = (const uint4*)c3o + (size_t)nl * 2048;
    const uint4* s1 = (const uint4*)g1p + (size_t)nl * 4096;
    const uint4* s2 = s1 + 2048;
    #pragma unroll
    for (int r = 0; r < 4; ++r) l4[tid + r * 512] = s0[tid + r * 512];
    __syncthreads();

    f32x16 acc[4];
    zacc<4>(acc);
    uint4 pf[4];
    // ph0 (self, in A) || prefetch pos -> B
    #pragma unroll
    for (int r = 0; r < 4; ++r) pf[r] = s1[tid + r * 512];
    mfma_phase<32, 32, 1, 4, 32, 8>(lds, 0, 8192, wf1, 3 * 512, acc, wid, lane);
    #pragma unroll
    for (int r = 0; r < 4; ++r) l4[2048 + tid + r * 512] = pf[r];
    __syncthreads();
    // ph1 (pos, in B) || prefetch neg -> A
    #pragma unroll
    for (int r = 0; r < 4; ++r) pf[r] = s2[tid + r * 512];
    mfma_phase<32, 32, 1, 4, 32, 8>(lds, 2048, 8192, wf1 + 512, 3 * 512, acc, wid, lane);
    #pragma unroll
    for (int r = 0; r < 4; ++r) l4[tid + r * 512] = pf[r];
    __syncthreads();
    // ph2 (neg, in A)
    mfma_phase<32, 32, 1, 4, 32, 8>(lds, 0, 8192, wf1 + 1024, 3 * 512, acc, wid, lane);
    conv_epi<32, 32, 0, 4, 32, 8, false>(lds, 4096, nullptr, b1, acc, wid, lane);
    __syncthreads();

    // m1c2: bufX -> bufY
    zacc<4>(acc);
    mfma_phase<32, 32, 1, 4, 32, 8>(lds, 4096, 8192, wf2,       2 * 512, acc, wid, lane);
    mfma_phase<32, 32, 1, 4, 32, 8>(lds, 6144, 8192, wf2 + 512, 2 * 512, acc, wid, lane);
    conv_epi<32, 32, 0, 4, 32, 8, false>(lds, 0, nullptr, b2, acc, wid, lane);
    __syncthreads();

    // m1c3: bufY -> [4096,6144)
    zacc<4>(acc);
    mfma_phase<32, 32, 1, 4, 32, 8>(lds, 0,    8192, wf3,       2 * 512, acc, wid, lane);
    mfma_phase<32, 32, 1, 4, 32, 8>(lds, 2048, 8192, wf3 + 512, 2 * 512, acc, wid, lane);
    conv_epi<32, 16, 0, 4, 32, 8, false>(lds, 4096, nullptr, b3, acc, wid, lane);
    __syncthreads();

    // ds1: stride-2, relu -> global
    zacc<1>(acc);
    mfma_phase<32, 16, 2, 1, 8, 8>(lds, 4096, 8192, wfd, 512, acc, wid, lane);
    conv_epi<16, 16, 1, 1, 8, 8, true>(lds, 0,
        (unsigned short*)ds1o + (size_t)nl * 4096, bd, acc, wid, lane);
}

// ---------------- k_mid2: m2c1 + m2c2 + m2c3 + ds2 fused (8 waves) ---------
__global__ __launch_bounds__(512) void k_mid2(
    const bf16* __restrict__ ds1o, const bf16* __restrict__ g2p,
    const unsigned short* __restrict__ wf1, const float* __restrict__ b1,
    const unsigned short* __restrict__ wf2, const float* __restrict__ b2,
    const unsigned short* __restrict__ wf3, const float* __restrict__ b3,
    const unsigned short* __restrict__ wfd, const float* __restrict__ bd,
    bf16* __restrict__ ds2o)
{
    // chunks: stageA [0,512), stageB [512,1024), bufX [1024,2048),
    //         bufY [0,1024), m2c3-out [1024,1536), zero 2048
    __shared__ __align__(16) short lds[2049 * 8];
    const int nl = blockIdx.x, tid = threadIdx.x;
    const int wid = tid >> 6, lane = tid & 63;
    if (tid < 8) lds[2048 * 8 + tid] = 0;

    uint4* l4 = (uint4*)lds;
    const uint4* s0 = (const uint4*)ds1o + (size_t)nl * 512;
    const uint4* s1 = (const uint4*)g2p + (size_t)nl * 1024;
    const uint4* s2 = s1 + 512;
    l4[tid] = s0[tid];
    __syncthreads();

    f32x16 acc[1];
    zacc<1>(acc);
    uint4 pf;
    pf = s1[tid];
    mfma_phase<16, 16, 1, 1, 8, 8>(lds, 0, 2048, wf1, 3 * 512, acc, wid, lane);
    l4[512 + tid] = pf;
    __syncthreads();
    pf = s2[tid];
    mfma_phase<16, 16, 1, 1, 8, 8>(lds, 512, 2048, wf1 + 512, 3 * 512, acc, wid, lane);
    l4[tid] = pf;
    __syncthreads();
    mfma_phase<16, 16, 1, 1, 8, 8>(lds, 0, 2048, wf1 + 1024, 3 * 512, acc, wid, lane);
    conv_epi<16, 32, 0, 1, 8, 8, false>(lds, 1024, nullptr, b1, acc, wid, lane);
    __syncthreads();

    zacc<1>(acc);
    mfma_phase<16, 16, 1, 1, 8, 8>(lds, 1024, 2048, wf2,       2 * 512, acc, wid, lane);
    mfma_phase<16, 16, 1, 1, 8, 8>(lds, 1536, 2048, wf2 + 512, 2 * 512, acc, wid, lane);
    conv_epi<16, 32, 0, 1, 8, 8, false>(lds, 0, nullptr, b2, acc, wid, lane);
    __syncthreads();

    zacc<1>(acc);
    mfma_phase<16, 16, 1, 1, 8, 8>(lds, 0,   2048, wf3,       2 * 512, acc, wid, lane);
    mfma_phase<16, 16, 1, 1, 8, 8>(lds, 512, 2048, wf3 + 512, 2 * 512, acc, wid, lane);
    conv_epi<16, 16, 0, 1, 8, 8, false>(lds, 1024, nullptr, b3, acc, wid, lane);
    __syncthreads();

    zacc<1>(acc);
    mfma_phase<16, 8, 2, 1, 2, 8>(lds, 1024, 2048, wfd, 512, acc, wid, lane);
    conv_epi<8, 16, 1, 1, 2, 8, true>(lds, 0,
        (unsigned short*)ds2o + (size_t)nl * 1024, bd, acc, wid, lane);
}

// ---------------- read-once LDS gather: pos/neg sums only ------------------
template<int NPIX>
__global__ __launch_bounds__(256) void k_gather2(
    const bf16* __restrict__ in, const int* __restrict__ cnt,
    const int* __restrict__ lst, bf16* __restrict__ out, int node_base)
{
    constexpr int CPN = 2 * NPIX;
    __shared__ __align__(16) uint4 s_in[16 * 128];
    __shared__ int s_pos[16], s_neg[16];

    const int gl = blockIdx.x, sp = blockIdx.y, tid = threadIdx.x;
    const int gn0 = node_base + gl * 16, nl0 = gl * 16;

    if (tid < 16) {
        int c = cnt[gn0 + tid]; if (c > 16) c = 16;
        int pm = 0, nm = 0;
        for (int k = 0; k < c; ++k) {
            int e = lst[(size_t)(gn0 + tid) * 16 + k];
            int sl = (e & 0x7FFFFFFF) - gn0;
            if ((unsigned)sl < 16u) { if (e < 0) nm |= 1 << sl; else pm |= 1 << sl; }
        }
        s_pos[tid] = pm; s_neg[tid] = nm;
    }
    const uint4* in4 = (const uint4*)in;
    #pragma unroll
    for (int k = 0; k < 8; ++k) {
        int i = tid + k * 256;
        int srcn = i >> 7, chk = i & 127;
        gload16(&in4[(size_t)(nl0 + srcn) * CPN + sp * 128 + chk], &s_in[i]);
    }
    __syncthreads();

    const int dh = tid >> 7, ch = tid & 127;
    int pm[8], nm[8];
    #pragma unroll
    for (int dl = 0; dl < 8; ++dl) {
        pm[dl] = __builtin_amdgcn_readfirstlane(s_pos[dh * 8 + dl]);
        nm[dl] = __builtin_amdgcn_readfirstlane(s_neg[dh * 8 + dl]);
    }

    float aP[8][8], aN[8][8];
    #pragma unroll
    for (int dl = 0; dl < 8; ++dl)
        #pragma unroll
        for (int j = 0; j < 8; ++j) { aP[dl][j] = 0.f; aN[dl][j] = 0.f; }

    for (int s = 0; s < 16; ++s) {
        union { uint4 v; unsigned short u[8]; } q;
        q.v = s_in[s * 128 + ch];
        float f[8];
        #pragma unroll
        for (int j = 0; j < 8; ++j) f[j] = bf2f(q.u[j]);
        #pragma unroll
        for (int dl = 0; dl < 8; ++dl) {
            if ((pm[dl] >> s) & 1) {
                #pragma unroll
                for (int j = 0; j < 8; ++j) aP[dl][j] += f[j];
            }
            if ((nm[dl] >> s) & 1) {
                #pragma unroll
                for (int j = 0; j < 8; ++j) aN[dl][j] += f[j];
            }
        }
    }

    uint4* out4 = (uint4*)out;
    #pragma unroll
    for (int dl = 0; dl < 8; ++dl) {
        int d = nl0 + dh * 8 + dl;
        out4[((size_t)d * 2 + 0) * CPN + sp * 128 + ch] = pack8(aP[dl]);
        out4[((size_t)d * 2 + 1) * CPN + sp * 128 + ch] = pack8(aN[dl]);
    }
}

// ---------------- k_tail3: d1 + d2 + d3 + pool fused (8 img/block) ---------
// LDS chunks: stage ds2o [0,1024), d1o [1024,5120), d2o [0,512), zero 5120.
__global__ __launch_bounds__(512) void k_tail3(
    const bf16* __restrict__ ds2o,
    const unsigned short* __restrict__ w1, const float* __restrict__ b1,
    const unsigned short* __restrict__ w2, const float* __restrict__ b2,
    const unsigned short* __restrict__ w3, const float* __restrict__ b3,
    const int* __restrict__ nd, const float* __restrict__ pw,
    float* __restrict__ out, int node_base)
{
    __shared__ __align__(16) short lds[5121 * 8];
    __shared__ float s_part[4][8];
    const int tid = threadIdx.x, wid = tid >> 6, lane = tid & 63;
    const int col = lane & 31, kg = lane >> 5;
    const int img0 = blockIdx.x * 8;
    if (tid < 8) lds[5120 * 8 + tid] = 0;

    const uint4* src = (const uint4*)ds2o + (size_t)img0 * 128;
    gload16(src + tid,       (uint4*)lds + tid);
    gload16(src + 512 + tid, (uint4*)lds + 512 + tid);
    __syncthreads();

    // ---- d1: 16ch 8x8 -> 256ch 4x4. MT=8, NT=4, 32 tiles, TPW=4, CIG=1 ----
    {
        f32x16 acc[4];
        zacc<4>(acc);
        #pragma unroll
        for (int t = 0; t < 4; ++t) {
            int tl = wid + 8 * t;
            int m = tl >> 2, n = tl & 3;
            int idx = n * 32 + col;
            int img = idx >> 4, px = idx & 15;
            int oy = px >> 2, ox = px & 3;
            #pragma unroll
            for (int kk = 0; kk < 9; ++kk) {
                int iy = 2 * oy + kk / 3 - 1, ix = 2 * ox + kk % 3 - 1;
                bool ok = ((unsigned)iy < 8u) && ((unsigned)ix < 8u);
                int chunk = ok ? (img * 128 + kg * 64 + iy * 8 + ix) : 5120;
                short8 wfr = *(const short8*)(w1 + ((size_t)(kk * 8 + m) * 64 + lane) * 8);
                acc[t] = __builtin_amdgcn_mfma_f32_32x32x16_bf16(
                    wfr, *(const short8*)(lds + (size_t)chunk * 8), acc[t], 0, 0, 0);
            }
        }
        // epilogue -> LDS d1o: chunk = 1024 + img*512 + cc*16 + px
        #pragma unroll
        for (int t = 0; t < 4; ++t) {
            int tl = wid + 8 * t;
            int m = tl >> 2, n = tl & 3;
            int idx = n * 32 + col;
            int img = idx >> 4, px = idx & 15;
            #pragma unroll
            for (int q = 0; q < 4; ++q) {
                float v[4];
                #pragma unroll
                for (int j = 0; j < 4; ++j) {
                    int co = m * 32 + q * 8 + kg * 4 + j;
                    float x = acc[t][4 * q + j] + b1[co];
                    v[j] = (x >= 0.f) ? x : 0.1f * x;
                }
                uint2 pk;
                pk.x = cvtpk(v[0], v[1]);
                pk.y = cvtpk(v[2], v[3]);
                *(uint2*)(lds + ((size_t)(1024 + img * 512 + (m * 4 + q) * 16 + px)) * 8
                          + kg * 4) = pk;
            }
        }
    }
    __syncthreads();

    // ---- d2: 256ch 4x4 -> 128ch 2x2. MT=4, NT=1, 4 tiles (wid<4), CIG=16 --
    {
        f32x16 acc;
        #pragma unroll
        for (int e = 0; e < 16; ++e) acc[e] = 0.f;
        int img = col >> 2, px = col & 3;
        int oy = px >> 1, ox = px & 1;
        int poff[9];
        #pragma unroll
        for (int kk = 0; kk < 9; ++kk) {
            int iy = 2 * oy + kk / 3 - 1, ix = 2 * ox + kk % 3 - 1;
            bool ok = ((unsigned)iy < 4u) && ((unsigned)ix < 4u);
            poff[kk] = ok ? (iy * 4 + ix) : -1;
        }
        if (wid < 4) {
            for (int cig = 0; cig < 16; ++cig) {
                #pragma unroll
                for (int kk = 0; kk < 9; ++kk) {
                    short8 wfr = *(const short8*)(w2 +
                        ((size_t)((kk * 16 + cig) * 4 + wid) * 64 + lane) * 8);
                    int chunk = (poff[kk] >= 0)
                              ? 1024 + img * 512 + (cig * 2 + kg) * 16 + poff[kk]
                              : 5120;
                    acc = __builtin_amdgcn_mfma_f32_32x32x16_bf16(
                        wfr, *(const short8*)(lds + (size_t)chunk * 8), acc, 0, 0, 0);
                }
            }
        }
        __syncthreads();
        if (wid < 4) {
            #pragma unroll
            for (int q = 0; q < 4; ++q) {
                float v[4];
                #pragma unroll
                for (int j = 0; j < 4; ++j) {
                    int co = wid * 32 + q * 8 + kg * 4 + j;
                    float x = acc[4 * q + j] + b2[co];
                    v[j] = (x >= 0.f) ? x : 0.1f * x;
                }
                uint2 pk;
                pk.x = cvtpk(v[0], v[1]);
                pk.y = cvtpk(v[2], v[3]);
                *(uint2*)(lds + ((size_t)(img * 64 + (wid * 4 + q) * 4 + px)) * 8
                          + kg * 4) = pk;
            }
        }
    }
    __syncthreads();

    // ---- d3 + pool: 128ch 2x2 -> 128ch 1x1 -> dot(pw) -> atomicAdd --------
    {
        if (wid < 4) {
            int img = col;
            bool live = col < 8;
            f32x16 acc;
            #pragma unroll
            for (int e = 0; e < 16; ++e) acc[e] = 0.f;
            for (int cig = 0; cig < 8; ++cig) {
                #pragma unroll
                for (int kk = 0; kk < 9; ++kk) {
                    int iy = kk / 3 - 1, ix = kk % 3 - 1;
                    bool ok = live && ((unsigned)iy < 2u) && ((unsigned)ix < 2u);
                    int chunk = ok ? (img * 64 + (cig * 2 + kg) * 4 + iy * 2 + ix) : 5120;
                    short8 wfr = *(const short8*)(w3 +
                        ((size_t)((kk * 8 + cig) * 4 + wid) * 64 + lane) * 8);
                    acc = __builtin_amdgcn_mfma_f32_32x32x16_bf16(
                        wfr, *(const short8*)(lds + (size_t)chunk * 8), acc, 0, 0, 0);
                }
            }
            float part = 0.f;
            #pragma unroll
            for (int r = 0; r < 16; ++r) {
                int co = wid * 32 + (r & 3) + 8 * (r >> 2) + 4 * kg;
                float v = acc[r] + b3[co];
                v = (v >= 0.f) ? v : 0.1f * v;
                part += v * pw[co];
            }
            part += __shfl_xor(part, 32, 64);
            if (kg == 0 && live) s_part[wid][col] = part;
        }
        __syncthreads();
        if (tid < 8) {
            float s = s_part[0][tid] + s_part[1][tid] + s_part[2][tid] + s_part[3][tid];
            int g = nd[node_base + img0 + tid];
            if (g < 0) g = 0; if (g >= N_GRAPHS) g = N_GRAPHS - 1;
            atomicAdd(&out[g], s);
        }
    }
}

// ---------------------------------------------------------------------------
extern "C" void kernel_launch(void* const* d_in, const int* in_sizes, int n_in,
                              void* d_out, int out_size, void* d_ws, size_t ws_size,
                              hipStream_t stream)
{
    const float* x     = (const float*)d_in[0];
    const float* t     = (const float*)d_in[1];
    const int*   edges = (const int*)d_in[2];
    const int*   nd    = (const int*)d_in[3];
    const float* w_t   = (const float*)d_in[4];
    const float* b_t   = (const float*)d_in[5];
    const float* c1w   = (const float*)d_in[6];
    const float* c1b   = (const float*)d_in[7];
    const float* c2w   = (const float*)d_in[8];
    const float* c2b   = (const float*)d_in[9];
    const float* c3w   = (const float*)d_in[10];
    const float* c3b   = (const float*)d_in[11];
    const float* m1c1w = (const float*)d_in[12];
    const float* m1c1b = (const float*)d_in[13];
    const float* m1c2w = (const float*)d_in[14];
    const float* m1c2b = (const float*)d_in[15];
    const float* m1c3w = (const float*)d_in[16];
    const float* m1c3b = (const float*)d_in[17];
    const float* ds1w  = (const float*)d_in[18];
    const float* ds1b  = (const float*)d_in[19];
    const float* m2c1w = (const float*)d_in[20];
    const float* m2c1b = (const float*)d_in[21];
    const float* m2c2w = (const float*)d_in[22];
    const float* m2c2b = (const float*)d_in[23];
    const float* m2c3w = (const float*)d_in[24];
    const float* m2c3b = (const float*)d_in[25];
    const float* ds2w  = (const float*)d_in[26];
    const float* ds2b  = (const float*)d_in[27];
    const float* d1w   = (const float*)d_in[28];
    const float* d1b   = (const float*)d_in[29];
    const float* d2w   = (const float*)d_in[30];
    const float* d2b   = (const float*)d_in[31];
    const float* d3w   = (const float*)d_in[32];
    const float* d3b   = (const float*)d_in[33];
    const float* pw    = (const float*)d_in[34];
    const float* pb    = (const float*)d_in[35];
    float* out = (float*)d_out;

    uint8_t* ws = (uint8_t*)d_ws;
    int* adj_cnt = (int*)ws;                         // [0, 4K)
    int* adj_lst = (int*)(ws + 4096);                // [4K, 68K)
    #define WF(i)  ((unsigned short*)(ws + (128u << 10) + (size_t)(i) * 32768))
    unsigned short* wt_ds1 = (unsigned short*)(ws + (416u  << 10));
    unsigned short* wt_ds2 = (unsigned short*)(ws + (428u  << 10));
    unsigned short* wt_d1  = (unsigned short*)(ws + (440u  << 10));
    unsigned short* wt_d2  = (unsigned short*)(ws + (512u  << 10));
    unsigned short* wt_d3  = (unsigned short*)(ws + (1088u << 10));

    // ---- adaptive chunking: liveness-packed pool, 120 KiB per node --------
    const size_t RESV = 2ull << 20;
    size_t avail = (ws_size > RESV) ? ws_size - RESV : 0;
    int ncap = (int)(avail / (120 * 1024));
    ncap = (ncap / 16) * 16;
    if (ncap < 16) ncap = 16;
    if (ncap > N_NODES) ncap = N_NODES;
    uint8_t* R = ws + RESV;
    #define NB(off_kb) (R + (size_t)(off_kb) * 1024 * ncap)

    bf16*  c3o  = (bf16*)NB(0);     // [0,32)
    bf16*  g1p  = (bf16*)NB(32);    // [32,96)
    bf16*  ds1o = (bf16*)NB(96);    // [96,104)
    bf16*  g2p  = (bf16*)NB(104);   // [104,120)
    bf16*  ds2o = (bf16*)NB(0);     // [0,2)    (c3o/g1p dead)

    int nE    = in_sizes[2] / 3;
    int per_g = nE / N_GRAPHS;

    // ---- single setup launch: weight prep + adjacency + out init ----------
    {
        PrepArgs pa;
        const float* wsrc[N_PREP] = { c1w, c2w, c3w, m1c1w, m1c2w, m1c3w,
                                      m2c1w, m2c2w, m2c3w, ds1w, ds2w,
                                      d1w, d2w, d3w };
        unsigned short* wdst[N_PREP] = { WF(0), WF(1), WF(2), WF(3), WF(4), WF(5),
                                         WF(6), WF(7), WF(8), wt_ds1, wt_ds2,
                                         wt_d1, wt_d2, wt_d3 };
        int cin_[N_PREP]  = { 9, 16, 16, 48, 32, 32, 48, 32, 32, 16, 16, 16, 256, 128 };
        int cout_[N_PREP] = { 16, 16, 16, 32, 32, 16, 32, 32, 16, 16, 16, 256, 128, 128 };
        int cig_[N_PREP]  = { 1, 1, 1, 3, 2, 2, 3, 2, 2, 1, 1, 1, 16, 8 };
        int mt_[N_PREP]   = { 1, 1, 1, 1, 1, 1, 1, 1, 1, 1, 1, 8, 4, 4 };
        int total = 0;
        for (int i = 0; i < N_PREP; ++i) {
            pa.w[i] = wsrc[i]; pa.o[i] = wdst[i];
            pa.cin[i] = cin_[i]; pa.cout[i] = cout_[i];
            pa.cig[i] = cig_[i]; pa.mt[i] = mt_[i];
            pa.base[i] = total;
            total += 9 * cig_[i] * mt_[i];
        }
        pa.prep_total = total;
        pa.edges = edges; pa.per_g = per_g;
        pa.adj_cnt = adj_cnt; pa.adj_lst = adj_lst;
        pa.out = out; pa.pb = pb;
        k_setup<<<total + 16 + 1, 64, 0, stream>>>(pa);
    }

    for (int nb = 0; nb < N_NODES; nb += ncap) {
        int nc = (N_NODES - nb < ncap) ? (N_NODES - nb) : ncap;
        int ng = nc / 16;

        k_front<<<nc, 512, 0, stream>>>(x, t, w_t, b_t,
            WF(0), c1b, WF(1), c2b, WF(2), c3b, c3o, nb);

        k_gather2<1024><<<dim3(ng, 16), 256, 0, stream>>>(c3o, adj_cnt, adj_lst, g1p, nb);

        k_mid1<<<nc, 512, 0, stream>>>(c3o, g1p,
            WF(3), m1c1b, WF(4), m1c2b, WF(5), m1c3b, wt_ds1, ds1b, ds1o);

        k_gather2<256><<<dim3(ng, 4), 256, 0, stream>>>(ds1o, adj_cnt, adj_lst, g2p, nb);

        k_mid2<<<nc, 512, 0, stream>>>(ds1o, g2p,
            WF(6), m2c1b, WF(7), m2c2b, WF(8), m2c3b, wt_ds2, ds2b, ds2o);

        k_tail3<<<nc / 8, 512, 0, stream>>>(ds2o,
            wt_d1, d1b, wt_d2, d2b, wt_d3, d3b, nd, pw, out, nb);
    }
    #undef NB
    #undef WF
}